// Round 2
// baseline (280.128 us; speedup 1.0000x reference)
//
#include <hip/hip_runtime.h>

#define LRC   0.01f
#define WCLIP 5.0f
#define LO   (-4.5951198501345898f)
#define HI   ( 4.5951198501345898f)

__device__ __forceinline__ unsigned short f2bf(float f) {
    unsigned int u = __float_as_uint(f);
    u += 0x7fffu + ((u >> 16) & 1u);          // RNE
    return (unsigned short)(u >> 16);
}
__device__ __forceinline__ float bflo(unsigned int p) { return __uint_as_float(p << 16); }
__device__ __forceinline__ float bfhi(unsigned int p) { return __uint_as_float(p & 0xffff0000u); }

// ---------------------------------------------------------------------------
// K1: distances -> idx.  Block (0..255) = 16 cmap rows (4 neurons) x 256 cols.
//     cmap/cbias are block-uniform -> scalar loads (s_load), NO LDS.
//     ctx chunks (32 k) double-buffered in VGPRs. Sequential-k fp32 fmaf
//     (same order as R0 -> identical idx bits).
//     Blocks 256..319: transpose logits (1024x256) -> lT (256x1024).
// ---------------------------------------------------------------------------
__global__ __launch_bounds__(256) void k1_idx_lt(
    const float* __restrict__ cmap,    // (4096, 512)
    const float* __restrict__ ctx,     // (512, 256)
    const float* __restrict__ cbias,   // (4096)
    const float* __restrict__ logits,  // (1024, 256)
    int*   __restrict__ idxb,          // (1024, 256)
    float* __restrict__ lT)            // (256, 1024)
{
    __shared__ float smem[64 * 68];    // transpose path only
    const int t   = threadIdx.x;
    const int blk = blockIdx.x;

    if (blk < 256) {
        const int m0 = blk << 4;               // first of 16 cmap rows
        const int b  = t;                      // batch column
        float acc[16];
        #pragma unroll
        for (int m = 0; m < 16; ++m) acc[m] = 0.f;

        float cva[32], cvb[32];
        #pragma unroll
        for (int k = 0; k < 32; ++k) cva[k] = ctx[k * 256 + b];

        for (int k0 = 0; k0 < 512; k0 += 64) {
            // prefetch chunk k0+32 into cvb
            #pragma unroll
            for (int k = 0; k < 32; ++k) cvb[k] = ctx[(k0 + 32 + k) * 256 + b];
            // compute chunk k0 from cva (cmap reads are uniform -> s_load)
            #pragma unroll
            for (int m = 0; m < 16; ++m) {
                const float* Ar = cmap + (m0 + m) * 512 + k0;
                #pragma unroll
                for (int k = 0; k < 32; ++k) acc[m] = fmaf(Ar[k], cva[k], acc[m]);
            }
            // prefetch chunk k0+64 into cva (guarded, uniform branch)
            if (k0 + 64 < 512) {
                #pragma unroll
                for (int k = 0; k < 32; ++k) cva[k] = ctx[(k0 + 64 + k) * 256 + b];
            }
            // compute chunk k0+32 from cvb
            #pragma unroll
            for (int m = 0; m < 16; ++m) {
                const float* Ar = cmap + (m0 + m) * 512 + k0 + 32;
                #pragma unroll
                for (int k = 0; k < 32; ++k) acc[m] = fmaf(Ar[k], cvb[k], acc[m]);
            }
        }
        // epilogue: 16 rows = neurons s0..s0+3, 4 maps each
        const int s0 = blk << 2;
        #pragma unroll
        for (int g = 0; g < 4; ++g) {
            int v = 0;
            #pragma unroll
            for (int mm = 0; mm < 4; ++mm)
                v |= (acc[(g << 2) + mm] > cbias[m0 + (g << 2) + mm]) ? (1 << mm) : 0;
            idxb[(s0 + g) * 256 + b] = v;
        }
    } else {
        // transpose one 64(i) x 64(b) tile of logits into lT
        float* T = smem;                              // T[b_local][68]
        const int bi = blk - 256;
        const int i0 = (bi >> 2) << 6;
        const int b0 = (bi & 3) << 6;
        #pragma unroll
        for (int rep = 0; rep < 4; rep++) {
            int flat4 = rep * 256 + t;
            int r = flat4 >> 4;                       // i-local
            int c = (flat4 & 15) << 2;                // b-local
            float4 v = *(const float4*)(logits + (i0 + r) * 256 + b0 + c);
            T[(c + 0) * 68 + r] = v.x;
            T[(c + 1) * 68 + r] = v.y;
            T[(c + 2) * 68 + r] = v.z;
            T[(c + 3) * 68 + r] = v.w;
        }
        __syncthreads();
        #pragma unroll
        for (int rep = 0; rep < 4; rep++) {
            int flat4 = rep * 256 + t;
            int r = flat4 >> 4;                       // b-local
            int c = (flat4 & 15) << 2;                // i-local
            *(float4*)(lT + (b0 + r) * 1024 + i0 + c) =
                *(const float4*)(T + r * 68 + c);
        }
    }
}

// ---------------------------------------------------------------------------
// K2: gathered forward dots + sigmoid + per-(s,j) last-b coefficient.
//     256 blocks x 1024 thr (16 waves): 4 neurons, q = i-quarter, b = column.
//     Weights staged in LDS as bf16 (exact for w=1/1024): ds_read_b64 gather,
//     16 rows -> 32 banks (broadcast, ~conflict-free). Register-prefetch of
//     chunk c0+1 issued before the compute barrier -> HBM overlaps compute.
// ---------------------------------------------------------------------------
__global__ __launch_bounds__(1024) void k2_fwd(
    const float* __restrict__ logits,   // (1024, 256)
    const float* __restrict__ targets,  // (256)
    const float* __restrict__ weights,  // (1024, 16, 1024)
    const float* __restrict__ bias,     // (1)
    const int*   __restrict__ idxb,     // (1024, 256)
    float* __restrict__ outp,           // d_out first 1024*256
    float* __restrict__ coefb,          // (16384)
    int*   __restrict__ colb)           // (16384)
{
    __shared__ unsigned short wlds[64 * 68];   // bf16, row stride 68
    __shared__ float red[3 * 4 * 256];         // partials from q=1..3
    __shared__ float sig_lds[4 * 256];
    __shared__ int   lastb[64];

    const int t  = threadIdx.x;
    const int b  = t & 255;
    const int q  = t >> 8;               // i-quarter 0..3
    const int s0 = blockIdx.x << 2;

    if (t < 64) lastb[t] = -1;

    int jg[4], rowoff[4];
    #pragma unroll
    for (int g = 0; g < 4; g++) {
        jg[g] = idxb[(s0 + g) * 256 + b];
        rowoff[g] = ((g << 4) + jg[g]) * 68;
    }

    // staging: thread covers (row r, 4 cols at c) of each 64x64 chunk
    const int r   = t >> 4;              // 0..63 = g*16 + j
    const int c   = (t & 15) << 2;       // 0..60
    const float* wsrc = weights + ((s0 + (r >> 4)) << 14) + ((r & 15) << 10) + c;
    const int ldsoff = r * 68 + c;

    float4 pf = *(const float4*)wsrc;    // chunk 0 prefetch

    float acc[4] = {0.f, 0.f, 0.f, 0.f};
    const int qq = q << 4;               // i-local base within chunk

    for (int c0 = 0; c0 < 16; ++c0) {
        __syncthreads();                 // previous chunk's readers done
        unsigned int p0 = (unsigned int)f2bf(pf.x) | ((unsigned int)f2bf(pf.y) << 16);
        unsigned int p1 = (unsigned int)f2bf(pf.z) | ((unsigned int)f2bf(pf.w) << 16);
        *(uint2*)(wlds + ldsoff) = make_uint2(p0, p1);
        float4 nf;
        if (c0 < 15) nf = *(const float4*)(wsrc + ((c0 + 1) << 6));  // in flight during compute
        __syncthreads();                 // staged chunk visible

        const int ibase = (c0 << 6) + qq;
        #pragma unroll
        for (int ii = 0; ii < 16; ii += 4) {
            const int i = ibase + ii;
            float l0 = logits[(i + 0) * 256 + b];
            float l1 = logits[(i + 1) * 256 + b];
            float l2 = logits[(i + 2) * 256 + b];
            float l3 = logits[(i + 3) * 256 + b];
            #pragma unroll
            for (int g = 0; g < 4; g++) {
                uint2 wp = *(const uint2*)(wlds + rowoff[g] + qq + ii);
                acc[g] = fmaf(bflo(wp.x), l0, acc[g]);
                acc[g] = fmaf(bfhi(wp.x), l1, acc[g]);
                acc[g] = fmaf(bflo(wp.y), l2, acc[g]);
                acc[g] = fmaf(bfhi(wp.y), l3, acc[g]);
            }
        }
        pf = nf;
    }

    // reduce i-quarters
    if (q > 0) {
        #pragma unroll
        for (int g = 0; g < 4; g++) red[((q - 1) * 4 + g) * 256 + b] = acc[g];
    }
    __syncthreads();
    if (q == 0) {
        #pragma unroll
        for (int g = 0; g < 4; g++) {
            float tot = acc[g] + red[(0 * 4 + g) * 256 + b]
                               + red[(1 * 4 + g) * 256 + b]
                               + red[(2 * 4 + g) * 256 + b];
            float outv = fminf(fmaxf(tot, LO), HI);
            if (s0 + g == 0) outv = bias[0];      // neuron 0 forced to bias
            outp[(s0 + g) * 256 + b] = outv;
            sig_lds[(g << 8) + b] = 1.f / (1.f + __expf(-outv));
        }
    }
    __syncthreads();
    if (q == 0) {
        #pragma unroll
        for (int g = 0; g < 4; g++)
            atomicMax(&lastb[(g << 4) + jg[g]], b);
    }
    __syncthreads();
    if (t < 64) {
        int g  = t >> 4;
        int bb = lastb[t];
        float cf = 0.f;
        if (bb >= 0) cf = LRC * (sig_lds[(g << 8) + bb] - targets[bb]);
        coefb[(s0 << 4) + t] = cf;
        colb [(s0 << 4) + t] = bb;
    }
}

// ---------------------------------------------------------------------------
// K3: streaming weight update  new_w = clamp(w - coef * lT[b*], +-5)  (or copy)
// ---------------------------------------------------------------------------
__global__ __launch_bounds__(256) void k3_update(
    const float* __restrict__ weights,
    const float* __restrict__ lT,
    const float* __restrict__ coefb,
    const int*   __restrict__ colb,
    float* __restrict__ outw)
{
    const int t  = threadIdx.x;
    const int r0 = blockIdx.x << 2;
    const int o  = t << 2;
    #pragma unroll
    for (int rr = 0; rr < 4; rr++) {
        const int row = r0 + rr;
        const int col = colb[row];        // uniform across block
        const float cf = coefb[row];
        float4 wv = *(const float4*)(weights + row * 1024 + o);
        float4 res;
        if (col >= 0) {
            float4 lv = *(const float4*)(lT + col * 1024 + o);
            res.x = fminf(fmaxf(wv.x - cf * lv.x, -WCLIP), WCLIP);
            res.y = fminf(fmaxf(wv.y - cf * lv.y, -WCLIP), WCLIP);
            res.z = fminf(fmaxf(wv.z - cf * lv.z, -WCLIP), WCLIP);
            res.w = fminf(fmaxf(wv.w - cf * lv.w, -WCLIP), WCLIP);
        } else {
            res = wv;                     // untouched row: verbatim copy
        }
        *(float4*)(outw + row * 1024 + o) = res;
    }
}

// ---------------------------------------------------------------------------
extern "C" void kernel_launch(void* const* d_in, const int* in_sizes, int n_in,
                              void* d_out, int out_size, void* d_ws, size_t ws_size,
                              hipStream_t stream) {
    const float* logits  = (const float*)d_in[0];   // (1024, 256)
    const float* ctx     = (const float*)d_in[1];   // (512, 256)
    const float* targets = (const float*)d_in[2];   // (256)
    const float* weights = (const float*)d_in[3];   // (1024, 16, 1024)
    const float* cmap    = (const float*)d_in[4];   // (1024, 4, 512)
    const float* cbias   = (const float*)d_in[5];   // (1024, 4, 1)
    const float* bias    = (const float*)d_in[6];   // (1)

    float* outp = (float*)d_out;                    // (1024, 256)
    float* outw = outp + 1024 * 256;                // (1024, 16, 1024)

    char* ws = (char*)d_ws;
    int*   idxb  = (int*)ws;                        // 1 MB
    float* lT    = (float*)(ws + (1 << 20));        // 1 MB
    float* coefb = (float*)(ws + (2 << 20));        // 64 KB
    int*   colb  = (int*)  (ws + (2 << 20) + (1 << 16)); // 64 KB

    k1_idx_lt<<<320, 256, 0, stream>>>(cmap, ctx, cbias, logits, idxb, lT);
    k2_fwd  <<<256, 1024, 0, stream>>>(logits, targets, weights, bias, idxb,
                                       outp, coefb, colb);
    k3_update<<<4096, 256, 0, stream>>>(weights, lT, coefb, colb, outw);
}

// Round 3
// 186.860 us; speedup vs baseline: 1.4991x; 1.4991x over previous
//
#include <hip/hip_runtime.h>

#define LRC   0.01f
#define WCLIP 5.0f
#define LO   (-4.5951198501345898f)
#define HI   ( 4.5951198501345898f)

__device__ __forceinline__ unsigned short f2bf(float f) {
    unsigned int u = __float_as_uint(f);
    u += 0x7fffu + ((u >> 16) & 1u);          // RNE
    return (unsigned short)(u >> 16);
}
__device__ __forceinline__ float bflo(unsigned int p) { return __uint_as_float(p << 16); }
__device__ __forceinline__ float bfhi(unsigned int p) { return __uint_as_float(p & 0xffff0000u); }

// ---------------------------------------------------------------------------
// K1: distances GEMM (4096x512 @ 512x256) -> idx. LDS-tiled (scalar-pipe
//     streaming was R1's mistake). 64x64 tile, 4x4/thread, BK=64,
//     register-prefetch of next tile overlaps HBM with the 64-step FMA loop.
//     Ascending-k fp32 fmaf chain == R0 bitwise (no idx flips observed).
//     Blocks 256..319: transpose logits (1024x256) -> lT (256x1024).
// ---------------------------------------------------------------------------
__global__ __launch_bounds__(256) void k1_idx_lt(
    const float* __restrict__ cmap,    // (4096, 512)
    const float* __restrict__ ctx,     // (512, 256)
    const float* __restrict__ cbias,   // (4096)
    const float* __restrict__ logits,  // (1024, 256)
    int*   __restrict__ idxb,          // (1024, 256)
    float* __restrict__ lT)            // (256, 1024)
{
    __shared__ __align__(16) float As[64 * 68];   // As[k][m], stride 68
    __shared__ __align__(16) float Bs[64 * 68];   // Bs[k][n], stride 68
    const int t   = threadIdx.x;
    const int blk = blockIdx.x;

    if (blk < 256) {
        const int gm = blk >> 2, gn = blk & 3;
        const int m0 = gm << 6, n0 = gn << 6;
        const int tm = t >> 4, tn = t & 15;

        // staging geometry: flat4 = rep*256 + t -> r = rep*16 + (t>>4), c = (t&15)*4
        const int rs = t >> 4;             // row step base
        const int cs = (t & 15) << 2;      // fixed 4-col offset

        float acc[4][4];
        #pragma unroll
        for (int i = 0; i < 4; i++)
            #pragma unroll
            for (int j = 0; j < 4; j++) acc[i][j] = 0.f;

        float4 va[4], vb[4];
        #pragma unroll
        for (int rep = 0; rep < 4; rep++) {
            va[rep] = *(const float4*)(cmap + (m0 + (rep << 4) + rs) * 512 + cs);
            vb[rep] = *(const float4*)(ctx + (((rep << 4) + rs)) * 256 + n0 + cs);
        }

        for (int k0 = 0; k0 < 512; k0 += 64) {
            __syncthreads();               // previous tile's readers done
            #pragma unroll
            for (int rep = 0; rep < 4; rep++) {
                const int r = (rep << 4) + rs;
                As[(cs + 0) * 68 + r] = va[rep].x;   // A transposed: As[k][m]
                As[(cs + 1) * 68 + r] = va[rep].y;
                As[(cs + 2) * 68 + r] = va[rep].z;
                As[(cs + 3) * 68 + r] = va[rep].w;
                *(float4*)(Bs + r * 68 + cs) = vb[rep];  // B natural: Bs[k][n]
            }
            if (k0 + 64 < 512) {           // next tile in flight during compute
                #pragma unroll
                for (int rep = 0; rep < 4; rep++) {
                    va[rep] = *(const float4*)(cmap + (m0 + (rep << 4) + rs) * 512 + k0 + 64 + cs);
                    vb[rep] = *(const float4*)(ctx + (k0 + 64 + (rep << 4) + rs) * 256 + n0 + cs);
                }
            }
            __syncthreads();               // staged tile visible

            const float* ap = As + (tm << 2);
            const float* bp = Bs + (tn << 2);
            #pragma unroll 8
            for (int k = 0; k < 64; ++k) {
                float4 a4 = *(const float4*)(ap + k * 68);
                float4 b4 = *(const float4*)(bp + k * 68);
                acc[0][0] = fmaf(a4.x, b4.x, acc[0][0]);
                acc[0][1] = fmaf(a4.x, b4.y, acc[0][1]);
                acc[0][2] = fmaf(a4.x, b4.z, acc[0][2]);
                acc[0][3] = fmaf(a4.x, b4.w, acc[0][3]);
                acc[1][0] = fmaf(a4.y, b4.x, acc[1][0]);
                acc[1][1] = fmaf(a4.y, b4.y, acc[1][1]);
                acc[1][2] = fmaf(a4.y, b4.z, acc[1][2]);
                acc[1][3] = fmaf(a4.y, b4.w, acc[1][3]);
                acc[2][0] = fmaf(a4.z, b4.x, acc[2][0]);
                acc[2][1] = fmaf(a4.z, b4.y, acc[2][1]);
                acc[2][2] = fmaf(a4.z, b4.z, acc[2][2]);
                acc[2][3] = fmaf(a4.z, b4.w, acc[2][3]);
                acc[3][0] = fmaf(a4.w, b4.x, acc[3][0]);
                acc[3][1] = fmaf(a4.w, b4.y, acc[3][1]);
                acc[3][2] = fmaf(a4.w, b4.z, acc[3][2]);
                acc[3][3] = fmaf(a4.w, b4.w, acc[3][3]);
            }
        }
        // epilogue: thread's 4 m-rows = neuron s's 4 context maps
        const int s = (gm << 4) + tm;              // m = m0 + tm*4 + i, s = m/4
        int4 iv;
        int* ivp = &iv.x;
        float cb[4];
        #pragma unroll
        for (int i = 0; i < 4; i++) cb[i] = cbias[(s << 2) + i];
        #pragma unroll
        for (int j = 0; j < 4; j++) {
            int v = 0;
            #pragma unroll
            for (int i = 0; i < 4; i++)
                v |= (acc[i][j] > cb[i]) ? (1 << i) : 0;
            ivp[j] = v;
        }
        *(int4*)(idxb + s * 256 + n0 + (tn << 2)) = iv;
    } else {
        // transpose one 64(i) x 64(b) tile of logits into lT
        float* T = As;                                // reuse
        const int bi = blk - 256;
        const int i0 = (bi >> 2) << 6;
        const int b0 = (bi & 3) << 6;
        #pragma unroll
        for (int rep = 0; rep < 4; rep++) {
            int flat4 = rep * 256 + t;
            int r = flat4 >> 4;                       // i-local
            int c = (flat4 & 15) << 2;                // b-local
            float4 v = *(const float4*)(logits + (i0 + r) * 256 + b0 + c);
            T[(c + 0) * 68 + r] = v.x;
            T[(c + 1) * 68 + r] = v.y;
            T[(c + 2) * 68 + r] = v.z;
            T[(c + 3) * 68 + r] = v.w;
        }
        __syncthreads();
        #pragma unroll
        for (int rep = 0; rep < 4; rep++) {
            int flat4 = rep * 256 + t;
            int r = flat4 >> 4;                       // b-local
            int c = (flat4 & 15) << 2;                // i-local
            *(float4*)(lT + (b0 + r) * 1024 + i0 + c) =
                *(const float4*)(T + r * 68 + c);
        }
    }
}

// ---------------------------------------------------------------------------
// K2: forward dots + sigmoid + per-(s,j) last-b coef + FUSED weight update.
//     256 blocks x 1024 thr: 4 neurons/block; q = i-quarter, b = column.
//     Weights staged to LDS as bf16 (exact for 1/1024) for the dot; the
//     update epilogue re-reads original fp32 weights (exact update) and
//     writes new_w directly -> k3 eliminated (saves 64MB re-read + launch).
// ---------------------------------------------------------------------------
__global__ __launch_bounds__(1024) void k2_fwd_upd(
    const float* __restrict__ logits,   // (1024, 256)
    const float* __restrict__ targets,  // (256)
    const float* __restrict__ weights,  // (1024, 16, 1024)
    const float* __restrict__ bias,     // (1)
    const int*   __restrict__ idxb,     // (1024, 256)
    const float* __restrict__ lT,       // (256, 1024)
    float* __restrict__ outp,           // d_out first 1024*256
    float* __restrict__ outw)           // d_out + 1024*256
{
    __shared__ unsigned short wlds[64 * 68];   // bf16, row stride 68
    __shared__ float red[3 * 4 * 256];         // partials from q=1..3
    __shared__ float sig_lds[4 * 256];
    __shared__ int   lastb[64];
    __shared__ float cf_lds[64];

    const int t  = threadIdx.x;
    const int b  = t & 255;
    const int q  = t >> 8;               // i-quarter 0..3
    const int s0 = blockIdx.x << 2;

    if (t < 64) lastb[t] = -1;

    int jg[4], rowoff[4];
    #pragma unroll
    for (int g = 0; g < 4; g++) {
        jg[g] = idxb[(s0 + g) * 256 + b];
        rowoff[g] = ((g << 4) + jg[g]) * 68;
    }

    // staging: thread covers (row r, 4 cols at c) of each 64x64 chunk
    const int r   = t >> 4;              // 0..63 = g*16 + j
    const int c   = (t & 15) << 2;       // 0..60
    const float* wsrc = weights + ((s0 + (r >> 4)) << 14) + ((r & 15) << 10) + c;
    const int ldsoff = r * 68 + c;

    float4 pf = *(const float4*)wsrc;    // chunk 0 prefetch

    float acc[4] = {0.f, 0.f, 0.f, 0.f};
    const int qq = q << 4;               // i-local base within chunk

    for (int c0 = 0; c0 < 16; ++c0) {
        __syncthreads();                 // previous chunk's readers done
        unsigned int p0 = (unsigned int)f2bf(pf.x) | ((unsigned int)f2bf(pf.y) << 16);
        unsigned int p1 = (unsigned int)f2bf(pf.z) | ((unsigned int)f2bf(pf.w) << 16);
        *(uint2*)(wlds + ldsoff) = make_uint2(p0, p1);
        float4 nf;
        if (c0 < 15) nf = *(const float4*)(wsrc + ((c0 + 1) << 6));  // in flight
        __syncthreads();                 // staged chunk visible

        const int ibase = (c0 << 6) + qq;
        #pragma unroll
        for (int ii = 0; ii < 16; ii += 4) {
            const int i = ibase + ii;
            float l0 = logits[(i + 0) * 256 + b];
            float l1 = logits[(i + 1) * 256 + b];
            float l2 = logits[(i + 2) * 256 + b];
            float l3 = logits[(i + 3) * 256 + b];
            #pragma unroll
            for (int g = 0; g < 4; g++) {
                uint2 wp = *(const uint2*)(wlds + rowoff[g] + qq + ii);
                acc[g] = fmaf(bflo(wp.x), l0, acc[g]);
                acc[g] = fmaf(bfhi(wp.x), l1, acc[g]);
                acc[g] = fmaf(bflo(wp.y), l2, acc[g]);
                acc[g] = fmaf(bfhi(wp.y), l3, acc[g]);
            }
        }
        pf = nf;
    }

    // reduce i-quarters
    if (q > 0) {
        #pragma unroll
        for (int g = 0; g < 4; g++) red[((q - 1) * 4 + g) * 256 + b] = acc[g];
    }
    __syncthreads();
    if (q == 0) {
        #pragma unroll
        for (int g = 0; g < 4; g++) {
            float tot = acc[g] + red[(0 * 4 + g) * 256 + b]
                               + red[(1 * 4 + g) * 256 + b]
                               + red[(2 * 4 + g) * 256 + b];
            float outv = fminf(fmaxf(tot, LO), HI);
            if (s0 + g == 0) outv = bias[0];      // neuron 0 forced to bias
            outp[(s0 + g) * 256 + b] = outv;
            sig_lds[(g << 8) + b] = 1.f / (1.f + __expf(-outv));
        }
    }
    __syncthreads();
    if (q == 0) {
        #pragma unroll
        for (int g = 0; g < 4; g++)
            atomicMax(&lastb[(g << 4) + jg[g]], b);
    }
    __syncthreads();
    if (t < 64) {
        int g  = t >> 4;
        int bb = lastb[t];
        float cfv = 0.f;
        if (bb >= 0) cfv = LRC * (sig_lds[(g << 8) + bb] - targets[bb]);
        cf_lds[t] = cfv;
    }
    __syncthreads();

    // ---- fused update epilogue: 64 rows x 1024 cols, fp32-exact ----
    const int er = t >> 4;               // row 0..63 = g*16 + j
    const int ec = (t & 15) << 2;        // col base 0..60
    const long rowbase = ((long)(s0 + (er >> 4)) << 14) + ((long)(er & 15) << 10);
    const int   col = lastb[er];         // uniform within 16-lane row group
    const float cf  = cf_lds[er];
    const float* lrow = lT + ((long)(col < 0 ? 0 : col) << 10);
    #pragma unroll 4
    for (int seg = 0; seg < 16; ++seg) {
        const int c2 = ec + (seg << 6);
        float4 wv = *(const float4*)(weights + rowbase + c2);
        float4 res = wv;                 // untouched row: verbatim copy
        if (col >= 0) {
            float4 lv = *(const float4*)(lrow + c2);
            res.x = fminf(fmaxf(wv.x - cf * lv.x, -WCLIP), WCLIP);
            res.y = fminf(fmaxf(wv.y - cf * lv.y, -WCLIP), WCLIP);
            res.z = fminf(fmaxf(wv.z - cf * lv.z, -WCLIP), WCLIP);
            res.w = fminf(fmaxf(wv.w - cf * lv.w, -WCLIP), WCLIP);
        }
        *(float4*)(outw + rowbase + c2) = res;
    }
}

// ---------------------------------------------------------------------------
extern "C" void kernel_launch(void* const* d_in, const int* in_sizes, int n_in,
                              void* d_out, int out_size, void* d_ws, size_t ws_size,
                              hipStream_t stream) {
    const float* logits  = (const float*)d_in[0];   // (1024, 256)
    const float* ctx     = (const float*)d_in[1];   // (512, 256)
    const float* targets = (const float*)d_in[2];   // (256)
    const float* weights = (const float*)d_in[3];   // (1024, 16, 1024)
    const float* cmap    = (const float*)d_in[4];   // (1024, 4, 512)
    const float* cbias   = (const float*)d_in[5];   // (1024, 4, 1)
    const float* bias    = (const float*)d_in[6];   // (1)

    float* outp = (float*)d_out;                    // (1024, 256)
    float* outw = outp + 1024 * 256;                // (1024, 16, 1024)

    char* ws = (char*)d_ws;
    int*   idxb = (int*)ws;                         // 1 MB
    float* lT   = (float*)(ws + (1 << 20));         // 1 MB

    k1_idx_lt <<<320, 256, 0, stream>>>(cmap, ctx, cbias, logits, idxb, lT);
    k2_fwd_upd<<<256, 1024, 0, stream>>>(logits, targets, weights, bias, idxb,
                                         lT, outp, outw);
}